// Round 8
// baseline (90.995 us; speedup 1.0000x reference)
//
#include <hip/hip_runtime.h>

#define GRIDN 256
#define NVOX (GRIDN * GRIDN * GRIDN)   // 16,777,216 voxels, 64 MiB fp32
#define NYT  16                        // y-tiles of 16 rows
#define NBKT (GRIDN * NYT)             // 4096 buckets: key = z*16 + (y>>4)
#define BCAP 512                       // bucket capacity (lambda ~122, P(ovf)~1e-25)

typedef float floatx4 __attribute__((ext_vector_type(4)));

// ---------------------------------------------------------------------------
// Bin the sparse points by (z, y-tile). One pass, fixed-capacity buckets.
// rec = {x | y<<8, feat bits}.
// ---------------------------------------------------------------------------
__global__ __launch_bounds__(256) void k_bin(const float* __restrict__ feats,
                                             const int* __restrict__ coords,
                                             int* __restrict__ cnt,
                                             int2* __restrict__ rec, int n) {
    int i = blockIdx.x * blockDim.x + threadIdx.x;
    if (i >= n) return;
    int d = coords[3 * i + 0];
    int h = coords[3 * i + 1];
    int w = coords[3 * i + 2];
    int key = d * NYT + (h >> 4);
    int slot = atomicAdd(&cnt[key], 1);
    if (slot < BCAP)
        rec[(size_t)key * BCAP + slot] = make_int2(w | (h << 8), __float_as_int(feats[i]));
}

// ---------------------------------------------------------------------------
// Sparse fused 5x5x5 box conv. Block = 256 thr, tile 64(x) x 16(y) x 8(z out),
// grid 2048 (8 blocks/CU -> 32 waves/CU). Per input slice zi:
//   B_top; scatter: for each point in the (zi, ytile) buckets overlapping the
//   window, 5 clipped LDS atomicAdds into Xp[buf][y-y0+2][x-2..x+2]  (=Xbox);
//   B_mid; y-pass (5 aligned float4 rows = Ybox); zero other buffer;
//   z-ring (registers, static shift = Zbox); float4 store of out[zi-2].
// Double-buffered Xp: zero(k->buf^1) overlaps ypass(k->buf); 2 barriers/slice.
// ---------------------------------------------------------------------------
#define TXF 64
#define TYF 16
#define ZS  8
__global__ __launch_bounds__(256) void k_fused_sparse(const int* __restrict__ cnt,
                                                      const int2* __restrict__ rec,
                                                      float* __restrict__ out) {
    __shared__ float Xp[2][TYF + 4][64];   // rows = raw y0-2..y0+17, cols x0..x0+63

    const int tid = threadIdx.x;
    // XCD-chunked swizzle: 2048 blocks, 8 XCDs, 256-block chunks
    // (one XCD = 4 contiguous z-slabs -> bucket reads stay in its L2).
    int wg  = blockIdx.x;
    int swz = (wg & 7) * 256 + (wg >> 3);
    const int x0 = (swz & 3) * TXF;
    const int y0 = ((swz >> 2) & 15) * TYF;
    const int z0 = (swz >> 6) * ZS;

    const int xq = (tid & 15) * 4;
    const int yy = tid >> 4;
    const int yt_lo = max(0, (y0 - 2) >> 4);
    const int yt_hi = min(NYT - 1, (y0 + TYF + 1) >> 4);

    // Prologue: zero both buffers.
    for (int idx = tid; idx < 2 * (TYF + 4) * 16; idx += 256)
        ((float4*)Xp)[idx] = make_float4(0.f, 0.f, 0.f, 0.f);

    float4 a0 = {0,0,0,0}, a1 = {0,0,0,0}, a2 = {0,0,0,0},
           a3 = {0,0,0,0}, a4 = {0,0,0,0};

    for (int zi = z0 - 2; zi < z0 + ZS + 2; ++zi) {
        const int cb = zi & 1;
        __syncthreads();                    // B_top: buf[cb] zeroed & prior reads done
        if ((unsigned)zi < (unsigned)GRIDN) {
            for (int yt = yt_lo; yt <= yt_hi; ++yt) {
                int b  = zi * NYT + yt;
                int nb = min(cnt[b], BCAP);
                const int2* rb = rec + (size_t)b * BCAP;
                for (int j = tid; j < nb; j += 256) {
                    int2 r = rb[j];
                    int x  = r.x & 255;
                    int y  = (r.x >> 8) & 255;
                    int ry = y - y0 + 2;           // row in window?
                    int cx = x - x0;               // taps cx-2..cx+2
                    if ((unsigned)ry < (unsigned)(TYF + 4) && (unsigned)(cx + 2) < 68u) {
                        float f = __int_as_float(r.y);
                        #pragma unroll
                        for (int dx = -2; dx <= 2; ++dx) {
                            int cc = cx + dx;
                            if ((unsigned)cc < 64u)
                                atomicAdd(&Xp[cb][ry][cc], f);
                        }
                    }
                }
            }
        }
        __syncthreads();                    // B_mid: scatter complete
        // y-pass: 5 aligned float4 rows of the x-expanded slice.
        float4 q0 = *(const float4*)&Xp[cb][yy + 0][xq];
        float4 q1 = *(const float4*)&Xp[cb][yy + 1][xq];
        float4 q2 = *(const float4*)&Xp[cb][yy + 2][xq];
        float4 q3 = *(const float4*)&Xp[cb][yy + 3][xq];
        float4 q4 = *(const float4*)&Xp[cb][yy + 4][xq];
        float4 v;
        v.x = q0.x + q1.x + q2.x + q3.x + q4.x;
        v.y = q0.y + q1.y + q2.y + q3.y + q4.y;
        v.z = q0.z + q1.z + q2.z + q3.z + q4.z;
        v.w = q0.w + q1.w + q2.w + q3.w + q4.w;
        // Zero the OTHER buffer for slice zi+1 (disjoint from all live reads).
        for (int idx = tid; idx < (TYF + 4) * 16; idx += 256)
            ((float4*)Xp[cb ^ 1])[idx] = make_float4(0.f, 0.f, 0.f, 0.f);
        // z-ring shift (static indices only).
        a0 = a1; a1 = a2; a2 = a3; a3 = a4; a4 = v;
        int zo = zi - 2;
        if (zo >= z0) {
            float4 s;
            s.x = a0.x + a1.x + a2.x + a3.x + a4.x;
            s.y = a0.y + a1.y + a2.y + a3.y + a4.y;
            s.z = a0.z + a1.z + a2.z + a3.z + a4.z;
            s.w = a0.w + a1.w + a2.w + a3.w + a4.w;
            float4* op = (float4*)(out + (size_t)zo * (GRIDN * GRIDN)
                                       + (size_t)(y0 + yy) * GRIDN + x0 + xq);
            *op = s;
        }
    }
}

// ---------------------------------------------------------------------------
// Fallback if ws is too small: zero out, then 125-way atomic expansion.
// ---------------------------------------------------------------------------
__global__ __launch_bounds__(256) void k_zero4(floatx4* __restrict__ p, int n4) {
    int stride = gridDim.x * blockDim.x;
    floatx4 z = {0.f, 0.f, 0.f, 0.f};
    for (int i = blockIdx.x * blockDim.x + threadIdx.x; i < n4; i += stride)
        __builtin_nontemporal_store(z, &p[i]);
}

__global__ void k_scatter125(const float* __restrict__ feats,
                             const int* __restrict__ coords,
                             float* __restrict__ out, int n) {
    int i = blockIdx.x * blockDim.x + threadIdx.x;
    if (i >= n) return;
    int d = coords[3 * i + 0];
    int h = coords[3 * i + 1];
    int w = coords[3 * i + 2];
    float f = feats[i];
    int d0 = max(d - 2, 0), d1 = min(d + 2, GRIDN - 1);
    int h0 = max(h - 2, 0), h1 = min(h + 2, GRIDN - 1);
    int w0 = max(w - 2, 0), w1 = min(w + 2, GRIDN - 1);
    for (int dd = d0; dd <= d1; ++dd)
        for (int hh = h0; hh <= h1; ++hh)
            for (int ww = w0; ww <= w1; ++ww)
                atomicAdd(&out[(dd * GRIDN + hh) * GRIDN + ww], f);
}

extern "C" void kernel_launch(void* const* d_in, const int* in_sizes, int n_in,
                              void* d_out, int out_size, void* d_ws, size_t ws_size,
                              hipStream_t stream) {
    const float* feats  = (const float*)d_in[0];
    const int*   coords = (const int*)d_in[1];
    float*       out    = (float*)d_out;
    int n = in_sizes[0];

    const size_t cnt_bytes = (size_t)NBKT * sizeof(int);
    const size_t rec_bytes = (size_t)NBKT * BCAP * sizeof(int2);

    if (ws_size >= cnt_bytes + rec_bytes) {
        int*  cnt = (int*)d_ws;
        int2* rec = (int2*)((char*)d_ws + cnt_bytes);
        hipMemsetAsync(cnt, 0, cnt_bytes, stream);
        k_bin<<<(n + 255) / 256, 256, 0, stream>>>(feats, coords, cnt, rec, n);
        k_fused_sparse<<<2048, 256, 0, stream>>>(cnt, rec, out);
    } else {
        k_zero4<<<4096, 256, 0, stream>>>((floatx4*)out, NVOX / 4);
        k_scatter125<<<(n + 255) / 256, 256, 0, stream>>>(feats, coords, out, n);
    }
}

// Round 9
// 82.159 us; speedup vs baseline: 1.1075x; 1.1075x over previous
//
#include <hip/hip_runtime.h>

#define GRIDN 256
#define NVOX (GRIDN * GRIDN * GRIDN)   // 16,777,216 voxels, 64 MiB fp32
#define NYT  16                        // y-tiles of 16 rows
#define NBKT (GRIDN * NYT)             // 4096 buckets: key = z*16 + (y>>4)
#define BCAP 512                       // bucket capacity (lambda ~122)
#define CSTR 32                        // cnt stride in ints (128 B -> 1 counter/line)

typedef float floatx4 __attribute__((ext_vector_type(4)));
typedef int   intx2   __attribute__((ext_vector_type(2)));

// ---------------------------------------------------------------------------
// Bin points by (z, y-tile). Padded counters (kill false sharing); NT record
// stores (leave lines CLEAN so consumer XCDs don't hit dirty-remote-L2 path).
// ---------------------------------------------------------------------------
__global__ __launch_bounds__(256) void k_bin(const float* __restrict__ feats,
                                             const int* __restrict__ coords,
                                             int* __restrict__ cnt,
                                             int2* __restrict__ rec, int n) {
    int i = blockIdx.x * blockDim.x + threadIdx.x;
    if (i >= n) return;
    int d = coords[3 * i + 0];
    int h = coords[3 * i + 1];
    int w = coords[3 * i + 2];
    int key = d * NYT + (h >> 4);
    int slot = atomicAdd(&cnt[key * CSTR], 1);
    if (slot < BCAP) {
        intx2 r;
        r.x = w | (h << 8);
        r.y = __float_as_int(feats[i]);
        __builtin_nontemporal_store(r, (intx2*)&rec[(size_t)key * BCAP + slot]);
    }
}

// ---------------------------------------------------------------------------
// Sparse fused 5x5x5 box conv, v2: LDS-cached bucket counts + record prefetch.
// Block = 256 thr, tile 64(x) x 16(y) x 8(z out), grid 2048.
// Prologue: preload all 12x3 bucket counts -> LDS; zero both Xp buffers.
// Per slice k (zi = z0-2+k), buffer cb = k&1:
//   B_top; issue prefetch of slice k+1 records (regs q0,q1);
//   scatter slice-k records (p0,p1 + rare slow path) into Xp[cb] (5 LDS atomics);
//   B_mid; y-pass (5 aligned float4 rows); zero Xp[cb^1]; z-ring; NT store.
// Record loads are in flight across B_mid + ypass + store + B_top.
// ---------------------------------------------------------------------------
#define TXF 64
#define TYF 16
#define ZS  8
__global__ __launch_bounds__(256) void k_fused_sparse(const int* __restrict__ cnt,
                                                      const int2* __restrict__ rec,
                                                      float* __restrict__ out) {
    __shared__ float Xp[2][TYF + 4][64];
    __shared__ int   cm[12][3];    // bucket counts per (slice k, ytile t)
    __shared__ int   cb_[12][3];   // bucket ids

    const int tid = threadIdx.x;
    // XCD-chunked swizzle: 2048 blocks, 8 XCDs, 256-block chunks.
    int wg  = blockIdx.x;
    int swz = (wg & 7) * 256 + (wg >> 3);
    const int x0 = (swz & 3) * TXF;
    const int y0 = ((swz >> 2) & 15) * TYF;
    const int z0 = (swz >> 6) * ZS;

    const int xq  = (tid & 15) * 4;
    const int yy  = tid >> 4;
    const int yt0 = y0 >> 4;

    // Prologue: preload 36 bucket counts; zero both buffers.
    if (tid < 36) {
        int k  = tid / 3, t = tid - 3 * k;
        int zi = z0 - 2 + k;
        int yt = yt0 - 1 + t;
        int m = 0, b = -1;
        if ((unsigned)zi < (unsigned)GRIDN && (unsigned)yt < (unsigned)NYT) {
            b = zi * NYT + yt;
            m = min(cnt[b * CSTR], BCAP);
        }
        cm[k][t]  = m;
        cb_[k][t] = b;
    }
    for (int idx = tid; idx < 2 * (TYF + 4) * 16; idx += 256)
        ((float4*)Xp)[idx] = make_float4(0.f, 0.f, 0.f, 0.f);
    __syncthreads();

    // Record fetch helper (j = global index into the slice's 3 concatenated buckets).
    auto load_rec = [&](int k, int j) -> int2 {
        int m0 = cm[k][0], m1 = cm[k][1];
        int b, s;
        if (j < m0)           { b = cb_[k][0]; s = j; }
        else if (j < m0 + m1) { b = cb_[k][1]; s = j - m0; }
        else                  { b = cb_[k][2]; s = j - m0 - m1; }
        return rec[(size_t)b * BCAP + s];
    };

    // Prefetch slice 0.
    int2 p0 = {0, 0}, p1 = {0, 0};
    {
        int M = cm[0][0] + cm[0][1] + cm[0][2];
        if (tid < M)       p0 = load_rec(0, tid);
        if (tid + 256 < M) p1 = load_rec(0, tid + 256);
    }

    float4 a0 = {0,0,0,0}, a1 = {0,0,0,0}, a2 = {0,0,0,0},
           a3 = {0,0,0,0}, a4 = {0,0,0,0};

    for (int k = 0; k < ZS + 4; ++k) {
        const int cbuf = k & 1;
        __syncthreads();                    // B_top: Xp[cbuf] zeroed; prior reads done
        // Issue prefetch for slice k+1 (independent; hides across this slice).
        int2 q0 = {0, 0}, q1 = {0, 0};
        if (k + 1 < ZS + 4) {
            int Mn = cm[k + 1][0] + cm[k + 1][1] + cm[k + 1][2];
            if (tid < Mn)       q0 = load_rec(k + 1, tid);
            if (tid + 256 < Mn) q1 = load_rec(k + 1, tid + 256);
        }
        // Scatter slice k into Xp[cbuf].
        const int M = cm[k][0] + cm[k][1] + cm[k][2];
        {
            auto scat = [&](int2 r) {
                int x  = r.x & 255;
                int y  = (r.x >> 8) & 255;
                int ry = y - y0 + 2;
                int cx = x - x0;
                if ((unsigned)ry < (unsigned)(TYF + 4) && (unsigned)(cx + 2) < 68u) {
                    float f = __int_as_float(r.y);
                    #pragma unroll
                    for (int dx = -2; dx <= 2; ++dx) {
                        int cc = cx + dx;
                        if ((unsigned)cc < 64u)
                            atomicAdd(&Xp[cbuf][ry][cc], f);
                    }
                }
            };
            if (tid < M)       scat(p0);
            if (tid + 256 < M) scat(p1);
            for (int j = tid + 512; j < M; j += 256)   // overflow slow path (~never)
                scat(load_rec(k, j));
        }
        __syncthreads();                    // B_mid: scatter complete
        // y-pass: 5 aligned float4 rows.
        float4 q0r = *(const float4*)&Xp[cbuf][yy + 0][xq];
        float4 q1r = *(const float4*)&Xp[cbuf][yy + 1][xq];
        float4 q2r = *(const float4*)&Xp[cbuf][yy + 2][xq];
        float4 q3r = *(const float4*)&Xp[cbuf][yy + 3][xq];
        float4 q4r = *(const float4*)&Xp[cbuf][yy + 4][xq];
        float4 v;
        v.x = q0r.x + q1r.x + q2r.x + q3r.x + q4r.x;
        v.y = q0r.y + q1r.y + q2r.y + q3r.y + q4r.y;
        v.z = q0r.z + q1r.z + q2r.z + q3r.z + q4r.z;
        v.w = q0r.w + q1r.w + q2r.w + q3r.w + q4r.w;
        // Zero the OTHER buffer for slice k+1 (disjoint from live reads).
        for (int idx = tid; idx < (TYF + 4) * 16; idx += 256)
            ((float4*)Xp[cbuf ^ 1])[idx] = make_float4(0.f, 0.f, 0.f, 0.f);
        // z-ring shift (static indices only).
        a0 = a1; a1 = a2; a2 = a3; a3 = a4; a4 = v;
        int zo = z0 + k - 4;                // = zi - 2
        if (k >= 4) {
            floatx4 s;
            s.x = a0.x + a1.x + a2.x + a3.x + a4.x;
            s.y = a0.y + a1.y + a2.y + a3.y + a4.y;
            s.z = a0.z + a1.z + a2.z + a3.z + a4.z;
            s.w = a0.w + a1.w + a2.w + a3.w + a4.w;
            floatx4* op = (floatx4*)(out + (size_t)zo * (GRIDN * GRIDN)
                                         + (size_t)(y0 + yy) * GRIDN + x0 + xq);
            __builtin_nontemporal_store(s, op);
        }
        p0 = q0; p1 = q1;
    }
}

// ---------------------------------------------------------------------------
// Fallback if ws is too small: zero out, then 125-way atomic expansion.
// ---------------------------------------------------------------------------
__global__ __launch_bounds__(256) void k_zero4(floatx4* __restrict__ p, int n4) {
    int stride = gridDim.x * blockDim.x;
    floatx4 z = {0.f, 0.f, 0.f, 0.f};
    for (int i = blockIdx.x * blockDim.x + threadIdx.x; i < n4; i += stride)
        __builtin_nontemporal_store(z, &p[i]);
}

__global__ void k_scatter125(const float* __restrict__ feats,
                             const int* __restrict__ coords,
                             float* __restrict__ out, int n) {
    int i = blockIdx.x * blockDim.x + threadIdx.x;
    if (i >= n) return;
    int d = coords[3 * i + 0];
    int h = coords[3 * i + 1];
    int w = coords[3 * i + 2];
    float f = feats[i];
    int d0 = max(d - 2, 0), d1 = min(d + 2, GRIDN - 1);
    int h0 = max(h - 2, 0), h1 = min(h + 2, GRIDN - 1);
    int w0 = max(w - 2, 0), w1 = min(w + 2, GRIDN - 1);
    for (int dd = d0; dd <= d1; ++dd)
        for (int hh = h0; hh <= h1; ++hh)
            for (int ww = w0; ww <= w1; ++ww)
                atomicAdd(&out[(dd * GRIDN + hh) * GRIDN + ww], f);
}

extern "C" void kernel_launch(void* const* d_in, const int* in_sizes, int n_in,
                              void* d_out, int out_size, void* d_ws, size_t ws_size,
                              hipStream_t stream) {
    const float* feats  = (const float*)d_in[0];
    const int*   coords = (const int*)d_in[1];
    float*       out    = (float*)d_out;
    int n = in_sizes[0];

    const size_t cnt_bytes = (size_t)NBKT * CSTR * sizeof(int);
    const size_t rec_bytes = (size_t)NBKT * BCAP * sizeof(int2);

    if (ws_size >= cnt_bytes + rec_bytes) {
        int*  cnt = (int*)d_ws;
        int2* rec = (int2*)((char*)d_ws + cnt_bytes);
        hipMemsetAsync(cnt, 0, cnt_bytes, stream);
        k_bin<<<(n + 255) / 256, 256, 0, stream>>>(feats, coords, cnt, rec, n);
        k_fused_sparse<<<2048, 256, 0, stream>>>(cnt, rec, out);
    } else {
        k_zero4<<<4096, 256, 0, stream>>>((floatx4*)out, NVOX / 4);
        k_scatter125<<<(n + 255) / 256, 256, 0, stream>>>(feats, coords, out, n);
    }
}

// Round 10
// 75.046 us; speedup vs baseline: 1.2125x; 1.0948x over previous
//
#include <hip/hip_runtime.h>

#define GRIDN 256
#define NVOX (GRIDN * GRIDN * GRIDN)   // 16,777,216 voxels, 64 MiB fp32
#define NYT  16                        // y-tiles of 16 rows
#define NBKT (GRIDN * NYT)             // 4096 buckets: key = z*16 + (y>>4)
#define BCAP 512                       // bucket capacity (lambda ~122)
#define CSTR 32                        // cnt stride in ints (128 B/counter)

typedef float floatx4 __attribute__((ext_vector_type(4)));

// Raw barrier: wait LDS ops only (lgkmcnt), do NOT drain vmcnt.
// __syncthreads() would emit s_waitcnt vmcnt(0) and kill cross-slice
// prefetch + force store-ack waits (the measured ~4400cyc/slice stall).
#define BAR_LDS()                                              \
    do {                                                       \
        asm volatile("s_waitcnt lgkmcnt(0)" ::: "memory");     \
        __builtin_amdgcn_sched_barrier(0);                     \
        __builtin_amdgcn_s_barrier();                          \
        __builtin_amdgcn_sched_barrier(0);                     \
    } while (0)

// ---------------------------------------------------------------------------
// Bin points by (z, y-tile). Padded counters (128B) kill false sharing.
// NORMAL record stores: 16 MB rec is LLC-resident; L2/LLC merges same-line
// slots (NT stores prevented merging -> 8B HBM dribble).
// ---------------------------------------------------------------------------
__global__ __launch_bounds__(256) void k_bin(const float* __restrict__ feats,
                                             const int* __restrict__ coords,
                                             int* __restrict__ cnt,
                                             int2* __restrict__ rec, int n) {
    int i = blockIdx.x * blockDim.x + threadIdx.x;
    if (i >= n) return;
    int d = coords[3 * i + 0];
    int h = coords[3 * i + 1];
    int w = coords[3 * i + 2];
    int key = d * NYT + (h >> 4);
    int slot = atomicAdd(&cnt[key * CSTR], 1);
    if (slot < BCAP)
        rec[(size_t)key * BCAP + slot] = make_int2(w | (h << 8), __float_as_int(feats[i]));
}

// ---------------------------------------------------------------------------
// Sparse fused 5x5x5 box conv, v3: raw lgkm-only barriers.
// Block = 256 thr, tile 64(x) x 16(y) x 8(z out), grid 2048.
// Per slice k: B_top; issue k+1 record prefetch (stays in flight ACROSS
// barriers now); scatter k records -> Xp[cb] (5 LDS atomics each);
// B_mid; y-pass; zero Xp[cb^1]; z-ring; NT store.
// All cross-wave hazards are LDS ops => lgkmcnt(0)+s_barrier is sufficient;
// global loads are ordered by register deps, output stores by kernel end.
// ---------------------------------------------------------------------------
#define TXF 64
#define TYF 16
#define ZS  8
__global__ __launch_bounds__(256) void k_fused_sparse(const int* __restrict__ cnt,
                                                      const int2* __restrict__ rec,
                                                      float* __restrict__ out) {
    __shared__ float Xp[2][TYF + 4][64];
    __shared__ int   cm[12][3];    // bucket counts per (slice k, ytile t)
    __shared__ int   cb_[12][3];   // bucket ids

    const int tid = threadIdx.x;
    // XCD-chunked swizzle: 2048 blocks, 8 XCDs, 256-block chunks.
    int wg  = blockIdx.x;
    int swz = (wg & 7) * 256 + (wg >> 3);
    const int x0 = (swz & 3) * TXF;
    const int y0 = ((swz >> 2) & 15) * TYF;
    const int z0 = (swz >> 6) * ZS;

    const int xq  = (tid & 15) * 4;
    const int yy  = tid >> 4;
    const int yt0 = y0 >> 4;

    // Prologue: preload 36 bucket counts; zero both buffers.
    if (tid < 36) {
        int k  = tid / 3, t = tid - 3 * k;
        int zi = z0 - 2 + k;
        int yt = yt0 - 1 + t;
        int m = 0, b = -1;
        if ((unsigned)zi < (unsigned)GRIDN && (unsigned)yt < (unsigned)NYT) {
            b = zi * NYT + yt;
            m = min(cnt[b * CSTR], BCAP);
        }
        cm[k][t]  = m;
        cb_[k][t] = b;
    }
    for (int idx = tid; idx < 2 * (TYF + 4) * 16; idx += 256)
        ((float4*)Xp)[idx] = make_float4(0.f, 0.f, 0.f, 0.f);
    BAR_LDS();

    auto load_rec = [&](int k, int j) -> int2 {
        int m0 = cm[k][0], m1 = cm[k][1];
        int b, s;
        if (j < m0)           { b = cb_[k][0]; s = j; }
        else if (j < m0 + m1) { b = cb_[k][1]; s = j - m0; }
        else                  { b = cb_[k][2]; s = j - m0 - m1; }
        return rec[(size_t)b * BCAP + s];
    };

    // Prefetch slice 0.
    int2 p0 = {0, 0}, p1 = {0, 0};
    {
        int M = cm[0][0] + cm[0][1] + cm[0][2];
        if (tid < M)       p0 = load_rec(0, tid);
        if (tid + 256 < M) p1 = load_rec(0, tid + 256);
    }

    float4 a0 = {0,0,0,0}, a1 = {0,0,0,0}, a2 = {0,0,0,0},
           a3 = {0,0,0,0}, a4 = {0,0,0,0};

    for (int k = 0; k < ZS + 4; ++k) {
        const int cbuf = k & 1;
        BAR_LDS();                          // B_top: Xp[cbuf] zeroed; prior reads done
        // Issue prefetch for slice k+1 (in flight across both barriers now).
        int2 q0 = {0, 0}, q1 = {0, 0};
        if (k + 1 < ZS + 4) {
            int Mn = cm[k + 1][0] + cm[k + 1][1] + cm[k + 1][2];
            if (tid < Mn)       q0 = load_rec(k + 1, tid);
            if (tid + 256 < Mn) q1 = load_rec(k + 1, tid + 256);
        }
        // Scatter slice k into Xp[cbuf].
        const int M = cm[k][0] + cm[k][1] + cm[k][2];
        {
            auto scat = [&](int2 r) {
                int x  = r.x & 255;
                int y  = (r.x >> 8) & 255;
                int ry = y - y0 + 2;
                int cx = x - x0;
                if ((unsigned)ry < (unsigned)(TYF + 4) && (unsigned)(cx + 2) < 68u) {
                    float f = __int_as_float(r.y);
                    #pragma unroll
                    for (int dx = -2; dx <= 2; ++dx) {
                        int cc = cx + dx;
                        if ((unsigned)cc < 64u)
                            atomicAdd(&Xp[cbuf][ry][cc], f);
                    }
                }
            };
            if (tid < M)       scat(p0);
            if (tid + 256 < M) scat(p1);
            for (int j = tid + 512; j < M; j += 256)   // overflow slow path (~never)
                scat(load_rec(k, j));
        }
        BAR_LDS();                          // B_mid: scatter complete
        // y-pass: 5 aligned float4 rows.
        float4 q0r = *(const float4*)&Xp[cbuf][yy + 0][xq];
        float4 q1r = *(const float4*)&Xp[cbuf][yy + 1][xq];
        float4 q2r = *(const float4*)&Xp[cbuf][yy + 2][xq];
        float4 q3r = *(const float4*)&Xp[cbuf][yy + 3][xq];
        float4 q4r = *(const float4*)&Xp[cbuf][yy + 4][xq];
        float4 v;
        v.x = q0r.x + q1r.x + q2r.x + q3r.x + q4r.x;
        v.y = q0r.y + q1r.y + q2r.y + q3r.y + q4r.y;
        v.z = q0r.z + q1r.z + q2r.z + q3r.z + q4r.z;
        v.w = q0r.w + q1r.w + q2r.w + q3r.w + q4r.w;
        // Zero the OTHER buffer for slice k+1 (disjoint from live reads).
        for (int idx = tid; idx < (TYF + 4) * 16; idx += 256)
            ((float4*)Xp[cbuf ^ 1])[idx] = make_float4(0.f, 0.f, 0.f, 0.f);
        // z-ring shift (static indices only).
        a0 = a1; a1 = a2; a2 = a3; a3 = a4; a4 = v;
        int zo = z0 + k - 4;                // = zi - 2
        if (k >= 4) {
            floatx4 s;
            s.x = a0.x + a1.x + a2.x + a3.x + a4.x;
            s.y = a0.y + a1.y + a2.y + a3.y + a4.y;
            s.z = a0.z + a1.z + a2.z + a3.z + a4.z;
            s.w = a0.w + a1.w + a2.w + a3.w + a4.w;
            floatx4* op = (floatx4*)(out + (size_t)zo * (GRIDN * GRIDN)
                                         + (size_t)(y0 + yy) * GRIDN + x0 + xq);
            __builtin_nontemporal_store(s, op);
        }
        p0 = q0; p1 = q1;
    }
}

// ---------------------------------------------------------------------------
// Fallback if ws is too small: zero out, then 125-way atomic expansion.
// ---------------------------------------------------------------------------
__global__ __launch_bounds__(256) void k_zero4(floatx4* __restrict__ p, int n4) {
    int stride = gridDim.x * blockDim.x;
    floatx4 z = {0.f, 0.f, 0.f, 0.f};
    for (int i = blockIdx.x * blockDim.x + threadIdx.x; i < n4; i += stride)
        __builtin_nontemporal_store(z, &p[i]);
}

__global__ void k_scatter125(const float* __restrict__ feats,
                             const int* __restrict__ coords,
                             float* __restrict__ out, int n) {
    int i = blockIdx.x * blockDim.x + threadIdx.x;
    if (i >= n) return;
    int d = coords[3 * i + 0];
    int h = coords[3 * i + 1];
    int w = coords[3 * i + 2];
    float f = feats[i];
    int d0 = max(d - 2, 0), d1 = min(d + 2, GRIDN - 1);
    int h0 = max(h - 2, 0), h1 = min(h + 2, GRIDN - 1);
    int w0 = max(w - 2, 0), w1 = min(w + 2, GRIDN - 1);
    for (int dd = d0; dd <= d1; ++dd)
        for (int hh = h0; hh <= h1; ++hh)
            for (int ww = w0; ww <= w1; ++ww)
                atomicAdd(&out[(dd * GRIDN + hh) * GRIDN + ww], f);
}

extern "C" void kernel_launch(void* const* d_in, const int* in_sizes, int n_in,
                              void* d_out, int out_size, void* d_ws, size_t ws_size,
                              hipStream_t stream) {
    const float* feats  = (const float*)d_in[0];
    const int*   coords = (const int*)d_in[1];
    float*       out    = (float*)d_out;
    int n = in_sizes[0];

    const size_t cnt_bytes = (size_t)NBKT * CSTR * sizeof(int);
    const size_t rec_bytes = (size_t)NBKT * BCAP * sizeof(int2);

    if (ws_size >= cnt_bytes + rec_bytes) {
        int*  cnt = (int*)d_ws;
        int2* rec = (int2*)((char*)d_ws + cnt_bytes);
        hipMemsetAsync(cnt, 0, cnt_bytes, stream);
        k_bin<<<(n + 255) / 256, 256, 0, stream>>>(feats, coords, cnt, rec, n);
        k_fused_sparse<<<2048, 256, 0, stream>>>(cnt, rec, out);
    } else {
        k_zero4<<<4096, 256, 0, stream>>>((floatx4*)out, NVOX / 4);
        k_scatter125<<<(n + 255) / 256, 256, 0, stream>>>(feats, coords, out, n);
    }
}